// Round 7
// baseline (3299.898 us; speedup 1.0000x reference)
//
#include <hip/hip_runtime.h>
#include <math.h>

// B=256, T=2048, H=150. Sequential GRU, relu'd hidden, scalar linear head.
// 1 block / batch element (256 blocks = 256 CUs), 512 threads.
//
// R7: the backend RA enforces its own occupancy-driven VGPR cap (~102 @512thr,
// ~64 @1024thr) and spills asm-pinned loop-invariant values to scratch rather
// than exceed it (R1-R6: VGPR_Count 56-92, ~L2-bound 3600-4640 cyc/step on
// weight reload traffic). Fix: bypass the allocator. The 150 W_hh weights of
// thread j live in EXPLICIT registers v100-v249, loaded by inline-asm
// global_load in a prologue asm block; the phase-1 dot product is one asm
// block per step (readlane -> s20..s27 rotating, v_fmac_f32 acc, sgpr, vNNN).
// Both asm blocks clobber v100-v249 so no compiler value live across them can
// sit there; the compiler's ~40-reg working set packs into v0-v99.
// Math is bit-identical to the R4 kernel that passed at absmax 4.9e-4:
// same 4 stride-4 fmac chains, same (a0+a1)+(a2+a3)+bhh, phase 2 unchanged.
// __launch_bounds__(512,2): 2 waves/EU -> 256-VGPR budget (we use 250).

#define BB 256
#define TT 2048
#define HH 150
#define H3 450

// Clobber list for the explicit weight registers v100..v249.
#define WCLOB \
  "v100","v101","v102","v103","v104","v105","v106","v107","v108","v109", \
  "v110","v111","v112","v113","v114","v115","v116","v117","v118","v119", \
  "v120","v121","v122","v123","v124","v125","v126","v127","v128","v129", \
  "v130","v131","v132","v133","v134","v135","v136","v137","v138","v139", \
  "v140","v141","v142","v143","v144","v145","v146","v147","v148","v149", \
  "v150","v151","v152","v153","v154","v155","v156","v157","v158","v159", \
  "v160","v161","v162","v163","v164","v165","v166","v167","v168","v169", \
  "v170","v171","v172","v173","v174","v175","v176","v177","v178","v179", \
  "v180","v181","v182","v183","v184","v185","v186","v187","v188","v189", \
  "v190","v191","v192","v193","v194","v195","v196","v197","v198","v199", \
  "v200","v201","v202","v203","v204","v205","v206","v207","v208","v209", \
  "v210","v211","v212","v213","v214","v215","v216","v217","v218","v219", \
  "v220","v221","v222","v223","v224","v225","v226","v227","v228","v229", \
  "v230","v231","v232","v233","v234","v235","v236","v237","v238","v239", \
  "v240","v241","v242","v243","v244","v245","v246","v247","v248","v249"

// One dot-product quad: broadcast h[4q..4q+3] via readlane into 4 SGPRs,
// fmac against explicit weight regs. Two SGPR sets (A: s20-23, B: s24-27)
// alternate between consecutive quads for WAR distance.
#define QA(q, r0, r1, r2, r3) \
  "v_readlane_b32 s20, %[hx], " #q "\n\t" \
  "v_readlane_b32 s21, %[hy], " #q "\n\t" \
  "v_readlane_b32 s22, %[hz], " #q "\n\t" \
  "v_readlane_b32 s23, %[hw], " #q "\n\t" \
  "v_fmac_f32 %[a0], s20, " r0 "\n\t" \
  "v_fmac_f32 %[a1], s21, " r1 "\n\t" \
  "v_fmac_f32 %[a2], s22, " r2 "\n\t" \
  "v_fmac_f32 %[a3], s23, " r3 "\n\t"
#define QB(q, r0, r1, r2, r3) \
  "v_readlane_b32 s24, %[hx], " #q "\n\t" \
  "v_readlane_b32 s25, %[hy], " #q "\n\t" \
  "v_readlane_b32 s26, %[hz], " #q "\n\t" \
  "v_readlane_b32 s27, %[hw], " #q "\n\t" \
  "v_fmac_f32 %[a0], s24, " r0 "\n\t" \
  "v_fmac_f32 %[a1], s25, " r1 "\n\t" \
  "v_fmac_f32 %[a2], s26, " r2 "\n\t" \
  "v_fmac_f32 %[a3], s27, " r3 "\n\t"

__global__ __launch_bounds__(512, 2) void gru_seq_kernel(
    const float* __restrict__ input,   // [B,T]
    const float* __restrict__ W_ih,    // [450,1]
    const float* __restrict__ W_hh,    // [450,150]
    const float* __restrict__ b_ih,    // [450]
    const float* __restrict__ b_hh,    // [450]
    const float* __restrict__ W_lin,   // [1,150]
    const float* __restrict__ b_lin,   // [1]
    float* __restrict__ out)           // [B,T]
{
    const int b    = blockIdx.x;
    const int tid  = threadIdx.x;
    const int lane = tid & 63;

    __shared__ float  xrow[TT];       // 8 KB: whole input row
    __shared__ float4 h4[64];         // h[0..149] zero-padded to 256 floats
    __shared__ float  pre[H3 + 2];
    __shared__ float  ypart[4];

    // ---- prologue -------------------------------------------------------
    ((float4*)xrow)[tid] = ((const float4*)(input + (size_t)b * TT))[tid];
    if (tid < 64) h4[tid] = make_float4(0.f, 0.f, 0.f, 0.f);
    if (tid < 4)  ypart[tid] = 0.f;

    const int row = (tid < H3) ? tid : (H3 - 1);
    const float* wr = W_hh + row * HH;

    const float bhh = (tid < H3) ? b_hh[tid] : 0.f;
    float wih_r = 0.f, wih_z = 0.f, wih_n = 0.f;
    float bih_r = 0.f, bih_z = 0.f, bih_n = 0.f, wlin = 0.f;
    if (tid < HH) {
        wih_r = W_ih[tid];          bih_r = b_ih[tid];
        wih_z = W_ih[HH + tid];     bih_z = b_ih[HH + tid];
        wih_n = W_ih[2 * HH + tid]; bih_n = b_ih[2 * HH + tid];
        wlin  = W_lin[tid];
    }
    const float blin = b_lin[0];
    float hreg = 0.f;
    float* outb = out + (size_t)b * TT;

    // Load this thread's 150 weights into explicit v100..v249.
    asm volatile(
        "global_load_dwordx4 v[100:103], %0, off\n\t"
        "global_load_dwordx4 v[104:107], %0, off offset:16\n\t"
        "global_load_dwordx4 v[108:111], %0, off offset:32\n\t"
        "global_load_dwordx4 v[112:115], %0, off offset:48\n\t"
        "global_load_dwordx4 v[116:119], %0, off offset:64\n\t"
        "global_load_dwordx4 v[120:123], %0, off offset:80\n\t"
        "global_load_dwordx4 v[124:127], %0, off offset:96\n\t"
        "global_load_dwordx4 v[128:131], %0, off offset:112\n\t"
        "global_load_dwordx4 v[132:135], %0, off offset:128\n\t"
        "global_load_dwordx4 v[136:139], %0, off offset:144\n\t"
        "global_load_dwordx4 v[140:143], %0, off offset:160\n\t"
        "global_load_dwordx4 v[144:147], %0, off offset:176\n\t"
        "global_load_dwordx4 v[148:151], %0, off offset:192\n\t"
        "global_load_dwordx4 v[152:155], %0, off offset:208\n\t"
        "global_load_dwordx4 v[156:159], %0, off offset:224\n\t"
        "global_load_dwordx4 v[160:163], %0, off offset:240\n\t"
        "global_load_dwordx4 v[164:167], %0, off offset:256\n\t"
        "global_load_dwordx4 v[168:171], %0, off offset:272\n\t"
        "global_load_dwordx4 v[172:175], %0, off offset:288\n\t"
        "global_load_dwordx4 v[176:179], %0, off offset:304\n\t"
        "global_load_dwordx4 v[180:183], %0, off offset:320\n\t"
        "global_load_dwordx4 v[184:187], %0, off offset:336\n\t"
        "global_load_dwordx4 v[188:191], %0, off offset:352\n\t"
        "global_load_dwordx4 v[192:195], %0, off offset:368\n\t"
        "global_load_dwordx4 v[196:199], %0, off offset:384\n\t"
        "global_load_dwordx4 v[200:203], %0, off offset:400\n\t"
        "global_load_dwordx4 v[204:207], %0, off offset:416\n\t"
        "global_load_dwordx4 v[208:211], %0, off offset:432\n\t"
        "global_load_dwordx4 v[212:215], %0, off offset:448\n\t"
        "global_load_dwordx4 v[216:219], %0, off offset:464\n\t"
        "global_load_dwordx4 v[220:223], %0, off offset:480\n\t"
        "global_load_dwordx4 v[224:227], %0, off offset:496\n\t"
        "global_load_dwordx4 v[228:231], %0, off offset:512\n\t"
        "global_load_dwordx4 v[232:235], %0, off offset:528\n\t"
        "global_load_dwordx4 v[236:239], %0, off offset:544\n\t"
        "global_load_dwordx4 v[240:243], %0, off offset:560\n\t"
        "global_load_dwordx4 v[244:247], %0, off offset:576\n\t"
        "global_load_dwordx2 v[248:249], %0, off offset:592\n\t"
        "s_waitcnt vmcnt(0)\n\t"
        :
        : "v"(wr)
        : WCLOB, "memory");

    __syncthreads();

    // ---- recurrence -----------------------------------------------------
    for (int t = 0; t < TT; ++t) {
        // phase 1: h . W_hh[row]. hv lane q holds h[4q..4q+3].
        // Accumulation order bit-identical to the passing R1/R4 kernels.
        float4 hv = h4[lane];
        float a0 = 0.f, a1 = 0.f, a2 = 0.f, a3 = 0.f;
        asm volatile(
            QA( 0, "v100", "v101", "v102", "v103")
            QB( 1, "v104", "v105", "v106", "v107")
            QA( 2, "v108", "v109", "v110", "v111")
            QB( 3, "v112", "v113", "v114", "v115")
            QA( 4, "v116", "v117", "v118", "v119")
            QB( 5, "v120", "v121", "v122", "v123")
            QA( 6, "v124", "v125", "v126", "v127")
            QB( 7, "v128", "v129", "v130", "v131")
            QA( 8, "v132", "v133", "v134", "v135")
            QB( 9, "v136", "v137", "v138", "v139")
            QA(10, "v140", "v141", "v142", "v143")
            QB(11, "v144", "v145", "v146", "v147")
            QA(12, "v148", "v149", "v150", "v151")
            QB(13, "v152", "v153", "v154", "v155")
            QA(14, "v156", "v157", "v158", "v159")
            QB(15, "v160", "v161", "v162", "v163")
            QA(16, "v164", "v165", "v166", "v167")
            QB(17, "v168", "v169", "v170", "v171")
            QA(18, "v172", "v173", "v174", "v175")
            QB(19, "v176", "v177", "v178", "v179")
            QA(20, "v180", "v181", "v182", "v183")
            QB(21, "v184", "v185", "v186", "v187")
            QA(22, "v188", "v189", "v190", "v191")
            QB(23, "v192", "v193", "v194", "v195")
            QA(24, "v196", "v197", "v198", "v199")
            QB(25, "v200", "v201", "v202", "v203")
            QA(26, "v204", "v205", "v206", "v207")
            QB(27, "v208", "v209", "v210", "v211")
            QA(28, "v212", "v213", "v214", "v215")
            QB(29, "v216", "v217", "v218", "v219")
            QA(30, "v220", "v221", "v222", "v223")
            QB(31, "v224", "v225", "v226", "v227")
            QA(32, "v228", "v229", "v230", "v231")
            QB(33, "v232", "v233", "v234", "v235")
            QA(34, "v236", "v237", "v238", "v239")
            QB(35, "v240", "v241", "v242", "v243")
            QA(36, "v244", "v245", "v246", "v247")
            // quad 37: only k=148,149 exist; original added fmac(0,0)=+0
            // to a2/a3, which is exact identity -- skipped.
            "v_readlane_b32 s24, %[hx], 37\n\t"
            "v_readlane_b32 s25, %[hy], 37\n\t"
            "v_fmac_f32 %[a0], s24, v248\n\t"
            "v_fmac_f32 %[a1], s25, v249\n\t"
            : [a0] "+v"(a0), [a1] "+v"(a1), [a2] "+v"(a2), [a3] "+v"(a3)
            : [hx] "v"(hv.x), [hy] "v"(hv.y), [hz] "v"(hv.z), [hw] "v"(hv.w)
            : "s20","s21","s22","s23","s24","s25","s26","s27", WCLOB);

        if (tid < H3) pre[tid] = (a0 + a1) + (a2 + a3) + bhh;
        __syncthreads();

        // phase 2: gates + hidden update (threads 0..149) -- identical to R4
        float yc = 0.f;
        if (tid < HH) {
            float x  = xrow[t];
            float gr = fmaf(x, wih_r, bih_r) + pre[tid];
            float gz = fmaf(x, wih_z, bih_z) + pre[HH + tid];
            float hn = pre[2 * HH + tid];
            float r  = 1.f / (1.f + __expf(-gr));
            float z  = 1.f / (1.f + __expf(-gz));
            float ta = fmaf(x, wih_n, bih_n) + r * hn;
            ta = fminf(fmaxf(ta, -15.f), 15.f);
            float e  = __expf(2.f * ta);
            float n  = (e - 1.f) / (e + 1.f);        // tanh
            float hnew = fmaf(z, hreg - n, n);       // (1-z)*n + z*h
            hnew = fmaxf(hnew, 0.f);                 // relu
            hreg = hnew;
            ((float*)h4)[tid] = hnew;
            yc = hnew * wlin;
        }
        if (tid < 192) {
            #pragma unroll
            for (int off = 32; off >= 1; off >>= 1)
                yc += __shfl_down(yc, off, 64);
            if (lane == 0) ypart[tid >> 6] = yc;
        }
        __syncthreads();
        if (tid == 0) outb[t] = ypart[0] + ypart[1] + ypart[2] + blin;
    }
}

extern "C" void kernel_launch(void* const* d_in, const int* in_sizes, int n_in,
                              void* d_out, int out_size, void* d_ws, size_t ws_size,
                              hipStream_t stream) {
    const float* input = (const float*)d_in[0];
    const float* W_ih  = (const float*)d_in[1];
    const float* W_hh  = (const float*)d_in[2];
    const float* b_ih  = (const float*)d_in[3];
    const float* b_hh  = (const float*)d_in[4];
    const float* W_lin = (const float*)d_in[5];
    const float* b_lin = (const float*)d_in[6];
    float* out = (float*)d_out;

    gru_seq_kernel<<<dim3(BB), dim3(512), 0, stream>>>(
        input, W_ih, W_hh, b_ih, b_hh, W_lin, b_lin, out);
}

// Round 8
// 2946.912 us; speedup vs baseline: 1.1198x; 1.1198x over previous
//
#include <hip/hip_runtime.h>
#include <math.h>

// B=256, T=2048, H=150. Sequential GRU, relu'd hidden, scalar linear head.
// 1 block / batch element (256 blocks = 256 CUs), 1024 threads.
//
// R8 = R6 mapping (k-split by accumulator pair -> 4 waves/SIMD, 76 wts/thread)
//    + R7 residency (weights in EXPLICIT regs v[52:127], asm-loaded, both asm
//      blocks clobber the range so the RA can't allocate into it; launch
//      bounds (1024,4) hard-cap 128 VGPRs)
//    + v_pk_fma_f32: packed fp32 FMA. The packed lanes ARE R6's (a0,a1)
//      accumulator pair -> bit-identical math, half the fmac instructions.
// Per quad: 2 readlane (s-pair) + 1 pk_fma. Readlanes batched 8-ahead
// (s20..s27 rotation) to amortize the VALU->SGPR->VALU hazard.
// Association (passed R6 at absmax 4.9e-4): preH = a0+a1 per k-half,
// pre = (preA+preB)+bhh; phase 2 copied verbatim from R6.

#define BB 256
#define TT 2048
#define HH 150
#define H3 450

typedef float fx2 __attribute__((ext_vector_type(2)));

// Clobber list for explicit weight registers v52..v127.
#define WCLOB \
  "v52","v53","v54","v55","v56","v57","v58","v59","v60","v61","v62","v63", \
  "v64","v65","v66","v67","v68","v69","v70","v71","v72","v73","v74","v75", \
  "v76","v77","v78","v79","v80","v81","v82","v83","v84","v85","v86","v87", \
  "v88","v89","v90","v91","v92","v93","v94","v95","v96","v97","v98","v99", \
  "v100","v101","v102","v103","v104","v105","v106","v107","v108","v109", \
  "v110","v111","v112","v113","v114","v115","v116","v117","v118","v119", \
  "v120","v121","v122","v123","v124","v125","v126","v127"

#define RL2(q, sA, sB) \
  "v_readlane_b32 " sA ", %[hA], " #q "\n\t" \
  "v_readlane_b32 " sB ", %[hB], " #q "\n\t"
#define PK(sp, vp) \
  "v_pk_fma_f32 %[acc], " sp ", " vp ", %[acc]\n\t"
// Batch of 4 quads: 8 readlanes then 4 pk_fmas (write->read distance >= 5).
#define B4(q0,q1,q2,q3, p0,p1,p2,p3) \
  RL2(q0,"s20","s21") RL2(q1,"s22","s23") RL2(q2,"s24","s25") RL2(q3,"s26","s27") \
  PK("s[20:21]", p0) PK("s[22:23]", p1) PK("s[24:25]", p2) PK("s[26:27]", p3)

__global__ __launch_bounds__(1024, 4) void gru_seq_kernel(
    const float* __restrict__ input,   // [B,T]
    const float* __restrict__ W_ih,    // [450,1]
    const float* __restrict__ W_hh,    // [450,150]
    const float* __restrict__ b_ih,    // [450]
    const float* __restrict__ b_hh,    // [450]
    const float* __restrict__ W_lin,   // [1,150]
    const float* __restrict__ b_lin,   // [1]
    float* __restrict__ out)           // [B,T]
{
    const int b    = blockIdx.x;
    const int tid  = threadIdx.x;
    const int lane = tid & 63;
    const int wid  = tid >> 6;         // 0..15
    const int half = wid & 1;          // wave-uniform accumulator-pair half
    const int row  = ((wid >> 1) << 6) + lane;   // 0..511
    const int act  = (row < H3);
    const int rowc = act ? row : (H3 - 1);

    __shared__ float  xrow[TT];        // 8 KB input row
    __shared__ float4 h4[64];          // h[0..149] zero-padded to 256 floats
    __shared__ float  preA[H3];        // a0+a1 partials (k half 0)
    __shared__ float  preB[H3];        // a2+a3 partials (k half 1)
    __shared__ float  ypart[4];

    // ---- prologue -------------------------------------------------------
    ((float2*)xrow)[tid] = ((const float2*)(input + (size_t)b * TT))[tid];
    if (tid < 64) h4[tid] = make_float4(0.f, 0.f, 0.f, 0.f);
    if (tid < 4)  ypart[tid] = 0.f;

    // Thread weights: wa_q = W[rowc][4q+2*half], wb_q = W[rowc][4q+1+2*half],
    // q = 0..37 (q=37 half1 is the zero pad). Strided dwordx2 loads into
    // explicit pairs v[52+2q : 53+2q].
    const float* wr = W_hh + rowc * HH + 2 * half;
    asm volatile(
        "global_load_dwordx2 v[52:53],   %0, off\n\t"
        "global_load_dwordx2 v[54:55],   %0, off offset:16\n\t"
        "global_load_dwordx2 v[56:57],   %0, off offset:32\n\t"
        "global_load_dwordx2 v[58:59],   %0, off offset:48\n\t"
        "global_load_dwordx2 v[60:61],   %0, off offset:64\n\t"
        "global_load_dwordx2 v[62:63],   %0, off offset:80\n\t"
        "global_load_dwordx2 v[64:65],   %0, off offset:96\n\t"
        "global_load_dwordx2 v[66:67],   %0, off offset:112\n\t"
        "global_load_dwordx2 v[68:69],   %0, off offset:128\n\t"
        "global_load_dwordx2 v[70:71],   %0, off offset:144\n\t"
        "global_load_dwordx2 v[72:73],   %0, off offset:160\n\t"
        "global_load_dwordx2 v[74:75],   %0, off offset:176\n\t"
        "global_load_dwordx2 v[76:77],   %0, off offset:192\n\t"
        "global_load_dwordx2 v[78:79],   %0, off offset:208\n\t"
        "global_load_dwordx2 v[80:81],   %0, off offset:224\n\t"
        "global_load_dwordx2 v[82:83],   %0, off offset:240\n\t"
        "global_load_dwordx2 v[84:85],   %0, off offset:256\n\t"
        "global_load_dwordx2 v[86:87],   %0, off offset:272\n\t"
        "global_load_dwordx2 v[88:89],   %0, off offset:288\n\t"
        "global_load_dwordx2 v[90:91],   %0, off offset:304\n\t"
        "global_load_dwordx2 v[92:93],   %0, off offset:320\n\t"
        "global_load_dwordx2 v[94:95],   %0, off offset:336\n\t"
        "global_load_dwordx2 v[96:97],   %0, off offset:352\n\t"
        "global_load_dwordx2 v[98:99],   %0, off offset:368\n\t"
        "global_load_dwordx2 v[100:101], %0, off offset:384\n\t"
        "global_load_dwordx2 v[102:103], %0, off offset:400\n\t"
        "global_load_dwordx2 v[104:105], %0, off offset:416\n\t"
        "global_load_dwordx2 v[106:107], %0, off offset:432\n\t"
        "global_load_dwordx2 v[108:109], %0, off offset:448\n\t"
        "global_load_dwordx2 v[110:111], %0, off offset:464\n\t"
        "global_load_dwordx2 v[112:113], %0, off offset:480\n\t"
        "global_load_dwordx2 v[114:115], %0, off offset:496\n\t"
        "global_load_dwordx2 v[116:117], %0, off offset:512\n\t"
        "global_load_dwordx2 v[118:119], %0, off offset:528\n\t"
        "global_load_dwordx2 v[120:121], %0, off offset:544\n\t"
        "global_load_dwordx2 v[122:123], %0, off offset:560\n\t"
        "global_load_dwordx2 v[124:125], %0, off offset:576\n\t"
        "s_waitcnt vmcnt(0)\n\t"
        :
        : "v"(wr)
        : WCLOB, "memory");
    // quad 37: half0 -> k=148,149 ; half1 -> zero pad (no OOB load: select a
    // safe address, then zero after the load).
    {
        const float* p37 = half ? wr : (wr + 148);
        float lw0 = p37[0], lw1 = p37[1];
        if (half) { lw0 = 0.f; lw1 = 0.f; }
        asm volatile("v_mov_b32 v126, %0\n\tv_mov_b32 v127, %1\n\t"
                     :: "v"(lw0), "v"(lw1) : "v126", "v127");
    }

    // Phase-2 constants (threads 0..149) -- verbatim from passing R6.
    float wih_r = 0.f, wih_z = 0.f, wih_n = 0.f;
    float bih_r = 0.f, bih_z = 0.f, bih_n = 0.f, wlin = 0.f;
    float bhh_r = 0.f, bhh_z = 0.f, bhh_n = 0.f;
    if (tid < HH) {
        wih_r = W_ih[tid];          bih_r = b_ih[tid];          bhh_r = b_hh[tid];
        wih_z = W_ih[HH + tid];     bih_z = b_ih[HH + tid];     bhh_z = b_hh[HH + tid];
        wih_n = W_ih[2 * HH + tid]; bih_n = b_ih[2 * HH + tid]; bhh_n = b_hh[2 * HH + tid];
        wlin  = W_lin[tid];
    }
    const float blin = b_lin[0];
    float hreg = 0.f;
    float* outb = out + (size_t)b * TT;
    float* preH = half ? preB : preA;

    __syncthreads();

    // ---- recurrence -----------------------------------------------------
    for (int t = 0; t < TT; ++t) {
        // phase 1: this thread's two stride-4 chains as ONE packed pair.
        // hv lane q holds h[4q..4q+3]; wave-uniform half selects components
        // BEFORE readlane, so rl(hA,q) broadcasts h[4q+2*half].
        float4 hv = h4[lane];
        float hA = half ? hv.z : hv.x;
        float hB = half ? hv.w : hv.y;
        fx2 acc; acc.x = 0.f; acc.y = 0.f;
        asm volatile(
            B4( 0, 1, 2, 3, "v[52:53]",  "v[54:55]",  "v[56:57]",  "v[58:59]")
            B4( 4, 5, 6, 7, "v[60:61]",  "v[62:63]",  "v[64:65]",  "v[66:67]")
            B4( 8, 9,10,11, "v[68:69]",  "v[70:71]",  "v[72:73]",  "v[74:75]")
            B4(12,13,14,15, "v[76:77]",  "v[78:79]",  "v[80:81]",  "v[82:83]")
            B4(16,17,18,19, "v[84:85]",  "v[86:87]",  "v[88:89]",  "v[90:91]")
            B4(20,21,22,23, "v[92:93]",  "v[94:95]",  "v[96:97]",  "v[98:99]")
            B4(24,25,26,27, "v[100:101]","v[102:103]","v[104:105]","v[106:107]")
            B4(28,29,30,31, "v[108:109]","v[110:111]","v[112:113]","v[114:115]")
            B4(32,33,34,35, "v[116:117]","v[118:119]","v[120:121]","v[122:123]")
            RL2(36, "s20", "s21") RL2(37, "s22", "s23")
            PK("s[20:21]", "v[124:125]") PK("s[22:23]", "v[126:127]")
            : [acc] "+v"(acc)
            : [hA] "v"(hA), [hB] "v"(hB)
            : "s20","s21","s22","s23","s24","s25","s26","s27", WCLOB);
        if (act) preH[row] = acc.x + acc.y;   // half0: a0+a1, half1: a2+a3
        __syncthreads();

        // phase 2: gates + hidden update (threads 0..149) -- verbatim R6.
        float yc = 0.f;
        if (tid < HH) {
            float x  = xrow[t];
            float pr = (preA[tid]          + preB[tid])          + bhh_r;
            float pz = (preA[HH + tid]     + preB[HH + tid])     + bhh_z;
            float pn = (preA[2 * HH + tid] + preB[2 * HH + tid]) + bhh_n;
            float gr = fmaf(x, wih_r, bih_r) + pr;
            float gz = fmaf(x, wih_z, bih_z) + pz;
            float r  = 1.f / (1.f + __expf(-gr));
            float z  = 1.f / (1.f + __expf(-gz));
            float ta = fmaf(x, wih_n, bih_n) + r * pn;
            ta = fminf(fmaxf(ta, -15.f), 15.f);
            float e  = __expf(2.f * ta);
            float n  = (e - 1.f) / (e + 1.f);        // tanh
            float hnew = fmaf(z, hreg - n, n);       // (1-z)*n + z*h
            hnew = fmaxf(hnew, 0.f);                 // relu
            hreg = hnew;
            ((float*)h4)[tid] = hnew;
            yc = hnew * wlin;
        }
        if (tid < 192) {
            #pragma unroll
            for (int off = 32; off >= 1; off >>= 1)
                yc += __shfl_down(yc, off, 64);
            if (lane == 0) ypart[wid] = yc;
        }
        __syncthreads();
        if (tid == 0) outb[t] = ypart[0] + ypart[1] + ypart[2] + blin;
    }
}

extern "C" void kernel_launch(void* const* d_in, const int* in_sizes, int n_in,
                              void* d_out, int out_size, void* d_ws, size_t ws_size,
                              hipStream_t stream) {
    const float* input = (const float*)d_in[0];
    const float* W_ih  = (const float*)d_in[1];
    const float* W_hh  = (const float*)d_in[2];
    const float* b_ih  = (const float*)d_in[3];
    const float* b_hh  = (const float*)d_in[4];
    const float* W_lin = (const float*)d_in[5];
    const float* b_lin = (const float*)d_in[6];
    float* out = (float*)d_out;

    gru_seq_kernel<<<dim3(BB), dim3(1024), 0, stream>>>(
        input, W_ih, W_hh, b_ih, b_hh, W_lin, b_lin, out);
}

// Round 9
// 2426.751 us; speedup vs baseline: 1.3598x; 1.2143x over previous
//
#include <hip/hip_runtime.h>
#include <math.h>

// B=256, T=2048, H=150. Sequential GRU, relu'd hidden, scalar linear head.
// 1 block / batch element (256 blocks = 256 CUs), 1024 threads.
//
// R9 = R8 (k-split pair mapping, explicit-reg weights v[52:127], pk_fma)
// minus the two per-step critical-path taxes R8's counters exposed
// (stall ~2600 cyc/step, constant across R7/R8):
//   1. NO global store inside the loop: y_t buffered in LDS yout[],
//      dumped coalesced after the loop. __syncthreads() => s_waitcnt
//      vmcnt(0) + s_barrier, so the old per-step outb[t] store put an
//      HBM-write drain on every step's first barrier.
//   2. NO shfl-tree y-reduction: "row 450" of phase 1 IS the W_lin dot
//      (pad lanes in waves 14/15 load W_lin instead of a clamped W_hh
//      row). Phase 1 of iteration t+1 yields y_t = preA[450]+preB[450]
//      +blin; thread 512 (idle in phase 2) writes it to yout. y is not
//      fed back, so its re-association is ~1e-6 noise. h math bit-exact.
// Loop runs t=0..TT inclusive (iteration TT supplies y_{TT-1}; h-update
// guarded off).

#define BB 256
#define TT 2048
#define HH 150
#define H3 450

typedef float fx2 __attribute__((ext_vector_type(2)));

// Clobber list for explicit weight registers v52..v127.
#define WCLOB \
  "v52","v53","v54","v55","v56","v57","v58","v59","v60","v61","v62","v63", \
  "v64","v65","v66","v67","v68","v69","v70","v71","v72","v73","v74","v75", \
  "v76","v77","v78","v79","v80","v81","v82","v83","v84","v85","v86","v87", \
  "v88","v89","v90","v91","v92","v93","v94","v95","v96","v97","v98","v99", \
  "v100","v101","v102","v103","v104","v105","v106","v107","v108","v109", \
  "v110","v111","v112","v113","v114","v115","v116","v117","v118","v119", \
  "v120","v121","v122","v123","v124","v125","v126","v127"

#define RL2(q, sA, sB) \
  "v_readlane_b32 " sA ", %[hA], " #q "\n\t" \
  "v_readlane_b32 " sB ", %[hB], " #q "\n\t"
#define PK(sp, vp) \
  "v_pk_fma_f32 %[acc], " sp ", " vp ", %[acc]\n\t"
// Batch of 4 quads: 8 readlanes then 4 pk_fmas (write->read distance >= 5).
#define B4(q0,q1,q2,q3, p0,p1,p2,p3) \
  RL2(q0,"s20","s21") RL2(q1,"s22","s23") RL2(q2,"s24","s25") RL2(q3,"s26","s27") \
  PK("s[20:21]", p0) PK("s[22:23]", p1) PK("s[24:25]", p2) PK("s[26:27]", p3)

__global__ __launch_bounds__(1024, 4) void gru_seq_kernel(
    const float* __restrict__ input,   // [B,T]
    const float* __restrict__ W_ih,    // [450,1]
    const float* __restrict__ W_hh,    // [450,150]
    const float* __restrict__ b_ih,    // [450]
    const float* __restrict__ b_hh,    // [450]
    const float* __restrict__ W_lin,   // [1,150]
    const float* __restrict__ b_lin,   // [1]
    float* __restrict__ out)           // [B,T]
{
    const int b    = blockIdx.x;
    const int tid  = threadIdx.x;
    const int lane = tid & 63;
    const int wid  = tid >> 6;         // 0..15
    const int half = wid & 1;          // wave-uniform accumulator-pair half
    const int row  = ((wid >> 1) << 6) + lane;   // 0..511
    const int act  = (row <= H3);      // rows 0..449 = W_hh, row 450 = W_lin
    const int rowc = (row < H3) ? row : (H3 - 1);

    __shared__ float  xrow[TT];        // 8 KB input row
    __shared__ float4 h4[64];          // h[0..149] zero-padded to 256 floats
    __shared__ float  preA[H3 + 2];    // partials, k half 0 (451 used)
    __shared__ float  preB[H3 + 2];    // partials, k half 1
    __shared__ float  yout[TT];        // 8 KB y buffer (no global ops in loop)

    // ---- prologue -------------------------------------------------------
    ((float2*)xrow)[tid] = ((const float2*)(input + (size_t)b * TT))[tid];
    if (tid < 64) h4[tid] = make_float4(0.f, 0.f, 0.f, 0.f);

    // Thread weights: wa_q = R[4q+2*half], wb_q = R[4q+1+2*half], q=0..37,
    // where R = W_hh[rowc] for rows<450, R = W_lin for row 450 (pad rows
    // 451..511 load row 449, results discarded). Strided dwordx2 loads into
    // explicit pairs v[52+2q : 53+2q].
    const float* wr = (row == H3) ? (W_lin + 2 * half)
                                  : (W_hh + rowc * HH + 2 * half);
    asm volatile(
        "global_load_dwordx2 v[52:53],   %0, off\n\t"
        "global_load_dwordx2 v[54:55],   %0, off offset:16\n\t"
        "global_load_dwordx2 v[56:57],   %0, off offset:32\n\t"
        "global_load_dwordx2 v[58:59],   %0, off offset:48\n\t"
        "global_load_dwordx2 v[60:61],   %0, off offset:64\n\t"
        "global_load_dwordx2 v[62:63],   %0, off offset:80\n\t"
        "global_load_dwordx2 v[64:65],   %0, off offset:96\n\t"
        "global_load_dwordx2 v[66:67],   %0, off offset:112\n\t"
        "global_load_dwordx2 v[68:69],   %0, off offset:128\n\t"
        "global_load_dwordx2 v[70:71],   %0, off offset:144\n\t"
        "global_load_dwordx2 v[72:73],   %0, off offset:160\n\t"
        "global_load_dwordx2 v[74:75],   %0, off offset:176\n\t"
        "global_load_dwordx2 v[76:77],   %0, off offset:192\n\t"
        "global_load_dwordx2 v[78:79],   %0, off offset:208\n\t"
        "global_load_dwordx2 v[80:81],   %0, off offset:224\n\t"
        "global_load_dwordx2 v[82:83],   %0, off offset:240\n\t"
        "global_load_dwordx2 v[84:85],   %0, off offset:256\n\t"
        "global_load_dwordx2 v[86:87],   %0, off offset:272\n\t"
        "global_load_dwordx2 v[88:89],   %0, off offset:288\n\t"
        "global_load_dwordx2 v[90:91],   %0, off offset:304\n\t"
        "global_load_dwordx2 v[92:93],   %0, off offset:320\n\t"
        "global_load_dwordx2 v[94:95],   %0, off offset:336\n\t"
        "global_load_dwordx2 v[96:97],   %0, off offset:352\n\t"
        "global_load_dwordx2 v[98:99],   %0, off offset:368\n\t"
        "global_load_dwordx2 v[100:101], %0, off offset:384\n\t"
        "global_load_dwordx2 v[102:103], %0, off offset:400\n\t"
        "global_load_dwordx2 v[104:105], %0, off offset:416\n\t"
        "global_load_dwordx2 v[106:107], %0, off offset:432\n\t"
        "global_load_dwordx2 v[108:109], %0, off offset:448\n\t"
        "global_load_dwordx2 v[110:111], %0, off offset:464\n\t"
        "global_load_dwordx2 v[112:113], %0, off offset:480\n\t"
        "global_load_dwordx2 v[114:115], %0, off offset:496\n\t"
        "global_load_dwordx2 v[116:117], %0, off offset:512\n\t"
        "global_load_dwordx2 v[118:119], %0, off offset:528\n\t"
        "global_load_dwordx2 v[120:121], %0, off offset:544\n\t"
        "global_load_dwordx2 v[122:123], %0, off offset:560\n\t"
        "global_load_dwordx2 v[124:125], %0, off offset:576\n\t"
        "s_waitcnt vmcnt(0)\n\t"
        :
        : "v"(wr)
        : WCLOB, "memory");
    // quad 37: half0 -> k=148,149 ; half1 -> zero pad (no OOB load).
    {
        const float* p37 = half ? wr : (wr + 148);
        float lw0 = p37[0], lw1 = p37[1];
        if (half) { lw0 = 0.f; lw1 = 0.f; }
        asm volatile("v_mov_b32 v126, %0\n\tv_mov_b32 v127, %1\n\t"
                     :: "v"(lw0), "v"(lw1) : "v126", "v127");
    }

    // Phase-2 constants (threads 0..149) -- verbatim from passing R6/R8.
    float wih_r = 0.f, wih_z = 0.f, wih_n = 0.f;
    float bih_r = 0.f, bih_z = 0.f, bih_n = 0.f;
    float bhh_r = 0.f, bhh_z = 0.f, bhh_n = 0.f;
    if (tid < HH) {
        wih_r = W_ih[tid];          bih_r = b_ih[tid];          bhh_r = b_hh[tid];
        wih_z = W_ih[HH + tid];     bih_z = b_ih[HH + tid];     bhh_z = b_hh[HH + tid];
        wih_n = W_ih[2 * HH + tid]; bih_n = b_ih[2 * HH + tid]; bhh_n = b_hh[2 * HH + tid];
    }
    const float blin = b_lin[0];
    float hreg = 0.f;
    float* outb = out + (size_t)b * TT;
    float* preH = half ? preB : preA;

    __syncthreads();

    // ---- recurrence -----------------------------------------------------
    // Iteration t: phase 1 dots h_{t-1}-state... precisely: h4 holds the
    // hidden AFTER iteration t-1; row-450 dot therefore equals y_{t-1}-blin.
    // Extra iteration t==TT supplies y_{TT-1}; its h-update is guarded off.
    for (int t = 0; t <= TT; ++t) {
        // phase 1: this thread's two stride-4 chains as ONE packed pair.
        float4 hv = h4[lane];
        float hA = half ? hv.z : hv.x;
        float hB = half ? hv.w : hv.y;
        fx2 acc; acc.x = 0.f; acc.y = 0.f;
        asm volatile(
            B4( 0, 1, 2, 3, "v[52:53]",  "v[54:55]",  "v[56:57]",  "v[58:59]")
            B4( 4, 5, 6, 7, "v[60:61]",  "v[62:63]",  "v[64:65]",  "v[66:67]")
            B4( 8, 9,10,11, "v[68:69]",  "v[70:71]",  "v[72:73]",  "v[74:75]")
            B4(12,13,14,15, "v[76:77]",  "v[78:79]",  "v[80:81]",  "v[82:83]")
            B4(16,17,18,19, "v[84:85]",  "v[86:87]",  "v[88:89]",  "v[90:91]")
            B4(20,21,22,23, "v[92:93]",  "v[94:95]",  "v[96:97]",  "v[98:99]")
            B4(24,25,26,27, "v[100:101]","v[102:103]","v[104:105]","v[106:107]")
            B4(28,29,30,31, "v[108:109]","v[110:111]","v[112:113]","v[114:115]")
            B4(32,33,34,35, "v[116:117]","v[118:119]","v[120:121]","v[122:123]")
            RL2(36, "s20", "s21") RL2(37, "s22", "s23")
            PK("s[20:21]", "v[124:125]") PK("s[22:23]", "v[126:127]")
            : [acc] "+v"(acc)
            : [hA] "v"(hA), [hB] "v"(hB)
            : "s20","s21","s22","s23","s24","s25","s26","s27", WCLOB);
        if (act) preH[row] = acc.x + acc.y;   // half0: a0+a1, half1: a2+a3
        __syncthreads();

        // phase 2: gates + hidden update (threads 0..149), skipped at t==TT.
        if (t < TT && tid < HH) {
            float x  = xrow[t];
            float pr = (preA[tid]          + preB[tid])          + bhh_r;
            float pz = (preA[HH + tid]     + preB[HH + tid])     + bhh_z;
            float pn = (preA[2 * HH + tid] + preB[2 * HH + tid]) + bhh_n;
            float gr = fmaf(x, wih_r, bih_r) + pr;
            float gz = fmaf(x, wih_z, bih_z) + pz;
            float r  = 1.f / (1.f + __expf(-gr));
            float z  = 1.f / (1.f + __expf(-gz));
            float ta = fmaf(x, wih_n, bih_n) + r * pn;
            ta = fminf(fmaxf(ta, -15.f), 15.f);
            float e  = __expf(2.f * ta);
            float n  = (e - 1.f) / (e + 1.f);        // tanh
            float hnew = fmaf(z, hreg - n, n);       // (1-z)*n + z*h
            hnew = fmaxf(hnew, 0.f);                 // relu
            hreg = hnew;
            ((float*)h4)[tid] = hnew;
        }
        // y_{t-1} = W_lin . h_{t-1} + blin, from phase-1 row 450.
        // Thread 512 (wave 8, idle in phase 2) keeps this off the gate chain.
        if (t > 0 && tid == 512) {
            yout[t - 1] = (preA[H3] + preB[H3]) + blin;
        }
        __syncthreads();
    }

    // ---- epilogue: coalesced y dump (the loop's only global traffic) -----
    ((float2*)outb)[tid] = ((const float2*)yout)[tid];
}

extern "C" void kernel_launch(void* const* d_in, const int* in_sizes, int n_in,
                              void* d_out, int out_size, void* d_ws, size_t ws_size,
                              hipStream_t stream) {
    const float* input = (const float*)d_in[0];
    const float* W_ih  = (const float*)d_in[1];
    const float* W_hh  = (const float*)d_in[2];
    const float* b_ih  = (const float*)d_in[3];
    const float* b_hh  = (const float*)d_in[4];
    const float* W_lin = (const float*)d_in[5];
    const float* b_lin = (const float*)d_in[6];
    float* out = (float*)d_out;

    gru_seq_kernel<<<dim3(BB), dim3(1024), 0, stream>>>(
        input, W_ih, W_hh, b_ih, b_hh, W_lin, b_lin, out);
}

// Round 10
// 1967.756 us; speedup vs baseline: 1.6770x; 1.2333x over previous
//
#include <hip/hip_runtime.h>
#include <math.h>

// B=256, T=2048, H=150. Sequential GRU, relu'd hidden, scalar linear head.
// 1 block / batch element (256 blocks = 256 CUs), 512 threads.
//
// R10 = R9 loop structure (no global ops in loop; y as phase-1 "row 450";
// LDS yout) + 2-ROW REUSE of each h-broadcast:
//   thread (half=wid&1 wave-uniform, idx=(wid>>1)*64+lane) owns rows
//   (idx, idx+225) for k-half `half`. Per quad: 2 readlane -> s-pair feeds
//   TWO pk_fmas (rowA, rowB): 1.0 inst/MAC vs R9's 1.5, half the readlanes
//   per MAC. Weights: 152 explicit regs v[100:251] (R7 proved v100-v249
//   allocatable at 512 thr with __launch_bounds__(512,2); 2x252<=512/SIMD).
// Association bit-exact per row (same two stride-4 chains, k-ascending,
// (preA+preB)+bhh). idx==225 computes the W_lin dot (y). Phase 2 verbatim.

#define BB 256
#define TT 2048
#define HH 150
#define H3 450

typedef float fx2 __attribute__((ext_vector_type(2)));

// Clobber list for explicit weight registers v100..v251.
#define WCLOB \
  "v100","v101","v102","v103","v104","v105","v106","v107","v108","v109", \
  "v110","v111","v112","v113","v114","v115","v116","v117","v118","v119", \
  "v120","v121","v122","v123","v124","v125","v126","v127","v128","v129", \
  "v130","v131","v132","v133","v134","v135","v136","v137","v138","v139", \
  "v140","v141","v142","v143","v144","v145","v146","v147","v148","v149", \
  "v150","v151","v152","v153","v154","v155","v156","v157","v158","v159", \
  "v160","v161","v162","v163","v164","v165","v166","v167","v168","v169", \
  "v170","v171","v172","v173","v174","v175","v176","v177","v178","v179", \
  "v180","v181","v182","v183","v184","v185","v186","v187","v188","v189", \
  "v190","v191","v192","v193","v194","v195","v196","v197","v198","v199", \
  "v200","v201","v202","v203","v204","v205","v206","v207","v208","v209", \
  "v210","v211","v212","v213","v214","v215","v216","v217","v218","v219", \
  "v220","v221","v222","v223","v224","v225","v226","v227","v228","v229", \
  "v230","v231","v232","v233","v234","v235","v236","v237","v238","v239", \
  "v240","v241","v242","v243","v244","v245","v246","v247","v248","v249", \
  "v250","v251"

#define RL2(q, sA, sB) \
  "v_readlane_b32 " sA ", %[hA], " #q "\n\t" \
  "v_readlane_b32 " sB ", %[hB], " #q "\n\t"
// Batch of 4 quads: 8 readlanes then 8 pk_fmas (two rows share each s-pair).
#define B4(q0,q1,q2,q3, pa0,pa1,pa2,pa3, pb0,pb1,pb2,pb3) \
  RL2(q0,"s20","s21") RL2(q1,"s22","s23") RL2(q2,"s24","s25") RL2(q3,"s26","s27") \
  "v_pk_fma_f32 %[accA], s[20:21], " pa0 ", %[accA]\n\t" \
  "v_pk_fma_f32 %[accB], s[20:21], " pb0 ", %[accB]\n\t" \
  "v_pk_fma_f32 %[accA], s[22:23], " pa1 ", %[accA]\n\t" \
  "v_pk_fma_f32 %[accB], s[22:23], " pb1 ", %[accB]\n\t" \
  "v_pk_fma_f32 %[accA], s[24:25], " pa2 ", %[accA]\n\t" \
  "v_pk_fma_f32 %[accB], s[24:25], " pb2 ", %[accB]\n\t" \
  "v_pk_fma_f32 %[accA], s[26:27], " pa3 ", %[accA]\n\t" \
  "v_pk_fma_f32 %[accB], s[26:27], " pb3 ", %[accB]\n\t"

__global__ __launch_bounds__(512, 2) void gru_seq_kernel(
    const float* __restrict__ input,   // [B,T]
    const float* __restrict__ W_ih,    // [450,1]
    const float* __restrict__ W_hh,    // [450,150]
    const float* __restrict__ b_ih,    // [450]
    const float* __restrict__ b_hh,    // [450]
    const float* __restrict__ W_lin,   // [1,150]
    const float* __restrict__ b_lin,   // [1]
    float* __restrict__ out)           // [B,T]
{
    const int b    = blockIdx.x;
    const int tid  = threadIdx.x;
    const int lane = tid & 63;
    const int wid  = tid >> 6;               // 0..7
    const int half = wid & 1;                // wave-uniform k-half
    const int idx  = ((wid >> 1) << 6) + lane;   // 0..255

    __shared__ float  xrow[TT];        // 8 KB input row
    __shared__ float4 h4[64];          // h[0..149] zero-padded to 256 floats
    __shared__ float  preA[H3 + 2];    // partials, k half 0 (451 used)
    __shared__ float  preB[H3 + 2];    // partials, k half 1
    __shared__ float  yout[TT];        // 8 KB y buffer (no global ops in loop)

    // ---- prologue -------------------------------------------------------
    ((float4*)xrow)[tid] = ((const float4*)(input + (size_t)b * TT))[tid];
    if (tid < 64) h4[tid] = make_float4(0.f, 0.f, 0.f, 0.f);

    // Row pointers: idx<225 -> rows (idx, idx+225); idx==225 -> y-row
    // (W_lin for both, store A only); idx>225 -> pad (safe clamped rows,
    // no store). Offsets select this thread's k-half.
    const int  p   = (idx < 225) ? idx : 224;
    const float* wrA = (idx == 225) ? (W_lin + 2 * half)
                                    : (W_hh + p * HH + 2 * half);
    const float* wrB = (idx == 225) ? (W_lin + 2 * half)
                                    : (W_hh + (p + 225) * HH + 2 * half);

    // Weights: quad q pair (k=4q+2h, 4q+1+2h): rowA -> v[100+2q:101+2q],
    // rowB -> v[176+2q:177+2q], q=0..36 via strided dwordx2; q=37 special.
    asm volatile(
        "global_load_dwordx2 v[100:101], %0, off\n\t"
        "global_load_dwordx2 v[102:103], %0, off offset:16\n\t"
        "global_load_dwordx2 v[104:105], %0, off offset:32\n\t"
        "global_load_dwordx2 v[106:107], %0, off offset:48\n\t"
        "global_load_dwordx2 v[108:109], %0, off offset:64\n\t"
        "global_load_dwordx2 v[110:111], %0, off offset:80\n\t"
        "global_load_dwordx2 v[112:113], %0, off offset:96\n\t"
        "global_load_dwordx2 v[114:115], %0, off offset:112\n\t"
        "global_load_dwordx2 v[116:117], %0, off offset:128\n\t"
        "global_load_dwordx2 v[118:119], %0, off offset:144\n\t"
        "global_load_dwordx2 v[120:121], %0, off offset:160\n\t"
        "global_load_dwordx2 v[122:123], %0, off offset:176\n\t"
        "global_load_dwordx2 v[124:125], %0, off offset:192\n\t"
        "global_load_dwordx2 v[126:127], %0, off offset:208\n\t"
        "global_load_dwordx2 v[128:129], %0, off offset:224\n\t"
        "global_load_dwordx2 v[130:131], %0, off offset:240\n\t"
        "global_load_dwordx2 v[132:133], %0, off offset:256\n\t"
        "global_load_dwordx2 v[134:135], %0, off offset:272\n\t"
        "global_load_dwordx2 v[136:137], %0, off offset:288\n\t"
        "global_load_dwordx2 v[138:139], %0, off offset:304\n\t"
        "global_load_dwordx2 v[140:141], %0, off offset:320\n\t"
        "global_load_dwordx2 v[142:143], %0, off offset:336\n\t"
        "global_load_dwordx2 v[144:145], %0, off offset:352\n\t"
        "global_load_dwordx2 v[146:147], %0, off offset:368\n\t"
        "global_load_dwordx2 v[148:149], %0, off offset:384\n\t"
        "global_load_dwordx2 v[150:151], %0, off offset:400\n\t"
        "global_load_dwordx2 v[152:153], %0, off offset:416\n\t"
        "global_load_dwordx2 v[154:155], %0, off offset:432\n\t"
        "global_load_dwordx2 v[156:157], %0, off offset:448\n\t"
        "global_load_dwordx2 v[158:159], %0, off offset:464\n\t"
        "global_load_dwordx2 v[160:161], %0, off offset:480\n\t"
        "global_load_dwordx2 v[162:163], %0, off offset:496\n\t"
        "global_load_dwordx2 v[164:165], %0, off offset:512\n\t"
        "global_load_dwordx2 v[166:167], %0, off offset:528\n\t"
        "global_load_dwordx2 v[168:169], %0, off offset:544\n\t"
        "global_load_dwordx2 v[170:171], %0, off offset:560\n\t"
        "global_load_dwordx2 v[172:173], %0, off offset:576\n\t"
        "global_load_dwordx2 v[176:177], %1, off\n\t"
        "global_load_dwordx2 v[178:179], %1, off offset:16\n\t"
        "global_load_dwordx2 v[180:181], %1, off offset:32\n\t"
        "global_load_dwordx2 v[182:183], %1, off offset:48\n\t"
        "global_load_dwordx2 v[184:185], %1, off offset:64\n\t"
        "global_load_dwordx2 v[186:187], %1, off offset:80\n\t"
        "global_load_dwordx2 v[188:189], %1, off offset:96\n\t"
        "global_load_dwordx2 v[190:191], %1, off offset:112\n\t"
        "global_load_dwordx2 v[192:193], %1, off offset:128\n\t"
        "global_load_dwordx2 v[194:195], %1, off offset:144\n\t"
        "global_load_dwordx2 v[196:197], %1, off offset:160\n\t"
        "global_load_dwordx2 v[198:199], %1, off offset:176\n\t"
        "global_load_dwordx2 v[200:201], %1, off offset:192\n\t"
        "global_load_dwordx2 v[202:203], %1, off offset:208\n\t"
        "global_load_dwordx2 v[204:205], %1, off offset:224\n\t"
        "global_load_dwordx2 v[206:207], %1, off offset:240\n\t"
        "global_load_dwordx2 v[208:209], %1, off offset:256\n\t"
        "global_load_dwordx2 v[210:211], %1, off offset:272\n\t"
        "global_load_dwordx2 v[212:213], %1, off offset:288\n\t"
        "global_load_dwordx2 v[214:215], %1, off offset:304\n\t"
        "global_load_dwordx2 v[216:217], %1, off offset:320\n\t"
        "global_load_dwordx2 v[218:219], %1, off offset:336\n\t"
        "global_load_dwordx2 v[220:221], %1, off offset:352\n\t"
        "global_load_dwordx2 v[222:223], %1, off offset:368\n\t"
        "global_load_dwordx2 v[224:225], %1, off offset:384\n\t"
        "global_load_dwordx2 v[226:227], %1, off offset:400\n\t"
        "global_load_dwordx2 v[228:229], %1, off offset:416\n\t"
        "global_load_dwordx2 v[230:231], %1, off offset:432\n\t"
        "global_load_dwordx2 v[232:233], %1, off offset:448\n\t"
        "global_load_dwordx2 v[234:235], %1, off offset:464\n\t"
        "global_load_dwordx2 v[236:237], %1, off offset:480\n\t"
        "global_load_dwordx2 v[238:239], %1, off offset:496\n\t"
        "global_load_dwordx2 v[240:241], %1, off offset:512\n\t"
        "global_load_dwordx2 v[242:243], %1, off offset:528\n\t"
        "global_load_dwordx2 v[244:245], %1, off offset:544\n\t"
        "global_load_dwordx2 v[246:247], %1, off offset:560\n\t"
        "global_load_dwordx2 v[248:249], %1, off offset:576\n\t"
        "s_waitcnt vmcnt(0)\n\t"
        :
        : "v"(wrA), "v"(wrB)
        : WCLOB, "memory");
    // quad 37: half0 -> real k=148,149 ; half1 -> zero pad (no OOB load).
    {
        const float* pA37 = half ? wrA : (wrA + 148);
        const float* pB37 = half ? wrB : (wrB + 148);
        float a0 = pA37[0], a1 = pA37[1];
        float c0 = pB37[0], c1 = pB37[1];
        if (half) { a0 = 0.f; a1 = 0.f; c0 = 0.f; c1 = 0.f; }
        asm volatile(
            "v_mov_b32 v174, %0\n\tv_mov_b32 v175, %1\n\t"
            "v_mov_b32 v250, %2\n\tv_mov_b32 v251, %3\n\t"
            :: "v"(a0), "v"(a1), "v"(c0), "v"(c1)
            : "v174","v175","v250","v251");
    }

    // Phase-2 constants (threads 0..149) -- verbatim from passing R9.
    float wih_r = 0.f, wih_z = 0.f, wih_n = 0.f;
    float bih_r = 0.f, bih_z = 0.f, bih_n = 0.f;
    float bhh_r = 0.f, bhh_z = 0.f, bhh_n = 0.f;
    if (tid < HH) {
        wih_r = W_ih[tid];          bih_r = b_ih[tid];          bhh_r = b_hh[tid];
        wih_z = W_ih[HH + tid];     bih_z = b_ih[HH + tid];     bhh_z = b_hh[HH + tid];
        wih_n = W_ih[2 * HH + tid]; bih_n = b_ih[2 * HH + tid]; bhh_n = b_hh[2 * HH + tid];
    }
    const float blin = b_lin[0];
    float hreg = 0.f;
    float* outb = out + (size_t)b * TT;
    float* preH = half ? preB : preA;

    __syncthreads();

    // ---- recurrence -----------------------------------------------------
    // Extra iteration t==TT supplies y_{TT-1}; its h-update is guarded off.
    for (int t = 0; t <= TT; ++t) {
        // phase 1: rows (idx, idx+225), this wave's k-half, 2 rl feed 2 pk.
        float4 hv = h4[lane];
        float hA = half ? hv.z : hv.x;
        float hB = half ? hv.w : hv.y;
        fx2 accA; accA.x = 0.f; accA.y = 0.f;
        fx2 accB; accB.x = 0.f; accB.y = 0.f;
        asm volatile(
            B4( 0, 1, 2, 3, "v[100:101]","v[102:103]","v[104:105]","v[106:107]",
                            "v[176:177]","v[178:179]","v[180:181]","v[182:183]")
            B4( 4, 5, 6, 7, "v[108:109]","v[110:111]","v[112:113]","v[114:115]",
                            "v[184:185]","v[186:187]","v[188:189]","v[190:191]")
            B4( 8, 9,10,11, "v[116:117]","v[118:119]","v[120:121]","v[122:123]",
                            "v[192:193]","v[194:195]","v[196:197]","v[198:199]")
            B4(12,13,14,15, "v[124:125]","v[126:127]","v[128:129]","v[130:131]",
                            "v[200:201]","v[202:203]","v[204:205]","v[206:207]")
            B4(16,17,18,19, "v[132:133]","v[134:135]","v[136:137]","v[138:139]",
                            "v[208:209]","v[210:211]","v[212:213]","v[214:215]")
            B4(20,21,22,23, "v[140:141]","v[142:143]","v[144:145]","v[146:147]",
                            "v[216:217]","v[218:219]","v[220:221]","v[222:223]")
            B4(24,25,26,27, "v[148:149]","v[150:151]","v[152:153]","v[154:155]",
                            "v[224:225]","v[226:227]","v[228:229]","v[230:231]")
            B4(28,29,30,31, "v[156:157]","v[158:159]","v[160:161]","v[162:163]",
                            "v[232:233]","v[234:235]","v[236:237]","v[238:239]")
            B4(32,33,34,35, "v[164:165]","v[166:167]","v[168:169]","v[170:171]",
                            "v[240:241]","v[242:243]","v[244:245]","v[246:247]")
            RL2(36, "s20", "s21") RL2(37, "s22", "s23")
            "v_pk_fma_f32 %[accA], s[20:21], v[172:173], %[accA]\n\t"
            "v_pk_fma_f32 %[accB], s[20:21], v[248:249], %[accB]\n\t"
            "v_pk_fma_f32 %[accA], s[22:23], v[174:175], %[accA]\n\t"
            "v_pk_fma_f32 %[accB], s[22:23], v[250:251], %[accB]\n\t"
            : [accA] "+v"(accA), [accB] "+v"(accB)
            : [hA] "v"(hA), [hB] "v"(hB)
            : "s20","s21","s22","s23","s24","s25","s26","s27", WCLOB);
        if (idx < 225) {
            preH[idx]       = accA.x + accA.y;
            preH[idx + 225] = accB.x + accB.y;
        } else if (idx == 225) {
            preH[H3]        = accA.x + accA.y;   // y-row (W_lin dot)
        }
        __syncthreads();

        // phase 2: gates + hidden update (threads 0..149), skipped at t==TT.
        if (t < TT && tid < HH) {
            float x  = xrow[t];
            float pr = (preA[tid]          + preB[tid])          + bhh_r;
            float pz = (preA[HH + tid]     + preB[HH + tid])     + bhh_z;
            float pn = (preA[2 * HH + tid] + preB[2 * HH + tid]) + bhh_n;
            float gr = fmaf(x, wih_r, bih_r) + pr;
            float gz = fmaf(x, wih_z, bih_z) + pz;
            float r  = 1.f / (1.f + __expf(-gr));
            float z  = 1.f / (1.f + __expf(-gz));
            float ta = fmaf(x, wih_n, bih_n) + r * pn;
            ta = fminf(fmaxf(ta, -15.f), 15.f);
            float e  = __expf(2.f * ta);
            float n  = (e - 1.f) / (e + 1.f);        // tanh
            float hnew = fmaf(z, hreg - n, n);       // (1-z)*n + z*h
            hnew = fmaxf(hnew, 0.f);                 // relu
            hreg = hnew;
            ((float*)h4)[tid] = hnew;
        }
        // y_{t-1} from phase-1 row 450; thread 450 is idle in phase 2.
        if (t > 0 && tid == 450) {
            yout[t - 1] = (preA[H3] + preB[H3]) + blin;
        }
        __syncthreads();
    }

    // ---- epilogue: coalesced y dump (the loop's only global write) -------
    ((float4*)outb)[tid] = ((const float4*)yout)[tid];
}

extern "C" void kernel_launch(void* const* d_in, const int* in_sizes, int n_in,
                              void* d_out, int out_size, void* d_ws, size_t ws_size,
                              hipStream_t stream) {
    const float* input = (const float*)d_in[0];
    const float* W_ih  = (const float*)d_in[1];
    const float* W_hh  = (const float*)d_in[2];
    const float* b_ih  = (const float*)d_in[3];
    const float* b_hh  = (const float*)d_in[4];
    const float* W_lin = (const float*)d_in[5];
    const float* b_lin = (const float*)d_in[6];
    float* out = (float*)d_out;

    gru_seq_kernel<<<dim3(BB), dim3(512), 0, stream>>>(
        input, W_ih, W_hh, b_ih, b_hh, W_lin, b_lin, out);
}